// Round 2
// baseline (38.524 us; speedup 1.0000x reference)
//
#include <hip/hip_runtime.h>

// MutualInformation2D: B=32 batches, N=2*512*512=524288 points/batch.
// hist (uint) per batch in d_ws, MI in double, scalar out = -mean(mi).

#define BINS 32
#define NBINS2 1024
#define LDS_ROW 33                       // padded row stride: bank = (iu+iv)%32
#define LDS_HIST (BINS * LDS_ROW)        // 1056
#define NBATCH 32
#define N_PER_BATCH (2 * 512 * 512)      // 524288
#define BLOCKS_PER_BATCH 64
#define CHUNK (N_PER_BATCH / BLOCKS_PER_BATCH)  // 8192 floats
#define THREADS 256
#define VEC_PER_THREAD (CHUNK / 4 / THREADS)    // 8 float4 per thread per array

__global__ __launch_bounds__(THREADS) void zero_kernel(unsigned* __restrict__ hist,
                                                       double* __restrict__ mi,
                                                       float* __restrict__ out) {
    int i = blockIdx.x * THREADS + threadIdx.x;
    if (i < NBATCH * NBINS2) hist[i] = 0u;
    if (i < NBATCH) mi[i] = 0.0;
    if (i == 0) out[0] = 0.0f;
}

__global__ __launch_bounds__(THREADS) void hist_kernel(const float* __restrict__ x,
                                                       const float* __restrict__ y,
                                                       unsigned* __restrict__ hist) {
    __shared__ unsigned h[LDS_HIST];
    for (int i = threadIdx.x; i < LDS_HIST; i += THREADS) h[i] = 0u;
    __syncthreads();

    const int b   = blockIdx.x / BLOCKS_PER_BATCH;
    const int blk = blockIdx.x % BLOCKS_PER_BATCH;
    const long base = (long)b * N_PER_BATCH + (long)blk * CHUNK;
    const float4* xv = (const float4*)(x + base);
    const float4* yv = (const float4*)(y + base);

    // Load the whole per-thread chunk up front: 16 independent float4 loads
    // in flight per wave (statically indexed -> stays in VGPRs).
    float4 xa[VEC_PER_THREAD], ya[VEC_PER_THREAD];
#pragma unroll
    for (int j = 0; j < VEC_PER_THREAD; ++j) xa[j] = xv[threadIdx.x + j * THREADS];
#pragma unroll
    for (int j = 0; j < VEC_PER_THREAD; ++j) ya[j] = yv[threadIdx.x + j * THREADS];

#pragma unroll
    for (int j = 0; j < VEC_PER_THREAD; ++j) {
        float ax[4] = {xa[j].x, xa[j].y, xa[j].z, xa[j].w};
        float ty[4] = {ya[j].x, ya[j].y, ya[j].z, ya[j].w};
#pragma unroll
        for (int k = 0; k < 4; ++k) {
            // Exact float32 replication of the reference binning.
            float u = (ax[k] + 1.0f) * 0.5f;
            float v = (ty[k] + 1.0f) * 0.5f;
            bool ok = (u >= 0.0f) & (u <= 1.0f) & (v >= 0.0f) & (v <= 1.0f);
            if (ok) {
                int iu = (int)(u * 32.0f); if (iu > 31) iu = 31;
                int iv = (int)(v * 32.0f); if (iv > 31) iv = 31;
                atomicAdd(&h[iu * LDS_ROW + iv], 1u);
            }
        }
    }
    __syncthreads();

    unsigned* g = hist + b * NBINS2;
    for (int i = threadIdx.x; i < NBINS2; i += THREADS) {
        unsigned v = h[(i >> 5) * LDS_ROW + (i & 31)];
        if (v) atomicAdd(&g[i], v);
    }
}

__global__ __launch_bounds__(256) void mi_kernel(const unsigned* __restrict__ hist,
                                                 double* __restrict__ mi_out) {
    __shared__ unsigned c[NBINS2];
    __shared__ unsigned px[BINS];
    __shared__ unsigned py[BINS];
    __shared__ double red[4];

    const int b = blockIdx.x;
    const unsigned* g = hist + b * NBINS2;
    for (int i = threadIdx.x; i < NBINS2; i += 256) c[i] = g[i];
    __syncthreads();

    if (threadIdx.x < 32) {
        unsigned s = 0;
        for (int j = 0; j < 32; ++j) s += c[threadIdx.x * BINS + j];
        px[threadIdx.x] = s;
    } else if (threadIdx.x < 64) {
        int col = threadIdx.x - 32;
        unsigned s = 0;
        for (int j = 0; j < 32; ++j) s += c[j * BINS + col];
        py[col] = s;
    }
    __syncthreads();

    unsigned total = 0;
    for (int j = 0; j < 32; ++j) total += px[j];
    const double T = (double)total;

    double acc = 0.0;
    for (int i = threadIdx.x; i < NBINS2; i += 256) {
        unsigned cc = c[i];
        if (cc) {
            int r = i >> 5, col = i & 31;
            acc += (double)cc * log((double)cc * T / ((double)px[r] * (double)py[col]));
        }
    }
    // wave (64-lane) shuffle reduction, fixed order -> deterministic
    for (int off = 32; off > 0; off >>= 1)
        acc += __shfl_down(acc, off, 64);
    int wave = threadIdx.x >> 6;
    if ((threadIdx.x & 63) == 0) red[wave] = acc;
    __syncthreads();
    if (threadIdx.x == 0) {
        double s = red[0] + red[1] + red[2] + red[3];
        mi_out[b] = s / T;
    }
}

__global__ void finalize_kernel(const double* __restrict__ mi, float* __restrict__ out) {
    if (threadIdx.x == 0) {
        double s = 0.0;
        for (int i = 0; i < NBATCH; ++i) s += mi[i];
        out[0] = (float)(-s / (double)NBATCH);
    }
}

extern "C" void kernel_launch(void* const* d_in, const int* in_sizes, int n_in,
                              void* d_out, int out_size, void* d_ws, size_t ws_size,
                              hipStream_t stream) {
    const float* x = (const float*)d_in[0];
    const float* y = (const float*)d_in[1];
    float* out = (float*)d_out;

    unsigned* hist = (unsigned*)d_ws;                                   // 32*1024*4 = 128 KiB
    double* mi = (double*)((char*)d_ws + NBATCH * NBINS2 * sizeof(unsigned)); // 256 B

    zero_kernel<<<(NBATCH * NBINS2 + THREADS - 1) / THREADS, THREADS, 0, stream>>>(hist, mi, out);
    hist_kernel<<<NBATCH * BLOCKS_PER_BATCH, THREADS, 0, stream>>>(x, y, hist);
    mi_kernel<<<NBATCH, 256, 0, stream>>>(hist, mi);
    finalize_kernel<<<1, 64, 0, stream>>>(mi, out);
}

// Round 3
// 35.652 us; speedup vs baseline: 1.0806x; 1.0806x over previous
//
#include <hip/hip_runtime.h>

// MutualInformation2D: B=32 batches, N=2*512*512=524288 points/batch.
// Per-block private histograms (plain stores, NO global atomics) -> per-batch
// integer reduction + MI in double -> scalar out = -mean(mi).

#define BINS 32
#define NBINS2 1024
#define LDS_ROW 33                       // padded row stride: bank = (iu+iv)%32
#define LDS_HIST (BINS * LDS_ROW)        // 1056
#define NBATCH 32
#define N_PER_BATCH (2 * 512 * 512)      // 524288
#define THREADS 256

template <int BPB>
__global__ __launch_bounds__(THREADS) void hist_kernel(const float* __restrict__ x,
                                                       const float* __restrict__ y,
                                                       unsigned* __restrict__ parts) {
    constexpr int CHUNKF = N_PER_BATCH / BPB;   // floats per block
    constexpr int NVEC   = CHUNKF / 4;          // float4 per block
    constexpr int TILE   = THREADS * 8;         // 2048 float4 per tile
    constexpr int NTILE  = NVEC / TILE;         // >=1

    __shared__ unsigned h[LDS_HIST];
    for (int i = threadIdx.x; i < LDS_HIST; i += THREADS) h[i] = 0u;
    __syncthreads();

    // Grid is batch-major, so blockIdx.x * NVEC is the right flat offset.
    const float4* xv = (const float4*)x + (size_t)blockIdx.x * NVEC;
    const float4* yv = (const float4*)y + (size_t)blockIdx.x * NVEC;

#pragma unroll
    for (int t = 0; t < NTILE; ++t) {
        // 16 independent float4 loads in flight per thread (static indices).
        float4 xa[8], ya[8];
#pragma unroll
        for (int j = 0; j < 8; ++j) xa[j] = xv[t * TILE + j * THREADS + threadIdx.x];
#pragma unroll
        for (int j = 0; j < 8; ++j) ya[j] = yv[t * TILE + j * THREADS + threadIdx.x];

#pragma unroll
        for (int j = 0; j < 8; ++j) {
            float ax[4] = {xa[j].x, xa[j].y, xa[j].z, xa[j].w};
            float ty[4] = {ya[j].x, ya[j].y, ya[j].z, ya[j].w};
#pragma unroll
            for (int k = 0; k < 4; ++k) {
                // Exact float32 replication of the reference binning.
                float u = (ax[k] + 1.0f) * 0.5f;
                float v = (ty[k] + 1.0f) * 0.5f;
                bool ok = (u >= 0.0f) & (u <= 1.0f) & (v >= 0.0f) & (v <= 1.0f);
                if (ok) {
                    int iu = (int)(u * 32.0f); if (iu > 31) iu = 31;
                    int iv = (int)(v * 32.0f); if (iv > 31) iv = 31;
                    atomicAdd(&h[iu * LDS_ROW + iv], 1u);
                }
            }
        }
    }
    __syncthreads();

    // Plain coalesced stores of the private histogram — no global atomics.
    unsigned* g = parts + (size_t)blockIdx.x * NBINS2;
    for (int i = threadIdx.x; i < NBINS2; i += THREADS)
        g[i] = h[(i >> 5) * LDS_ROW + (i & 31)];
}

__global__ __launch_bounds__(1024) void mi_kernel(const unsigned* __restrict__ parts,
                                                  int nparts,
                                                  double* __restrict__ mi_out) {
    __shared__ unsigned c[NBINS2];
    __shared__ unsigned px[BINS];
    __shared__ unsigned py[BINS];
    __shared__ double red[16];

    const int b = blockIdx.x;
    // Reduce partials: thread i owns bin i. Integer adds -> order-independent.
    const unsigned* base = parts + (size_t)b * nparts * NBINS2 + threadIdx.x;
    unsigned s = 0;
#pragma unroll 8
    for (int p = 0; p < nparts; ++p) s += base[(size_t)p * NBINS2];
    c[threadIdx.x] = s;
    __syncthreads();

    if (threadIdx.x < 32) {
        unsigned r = 0;
        for (int j = 0; j < 32; ++j) r += c[threadIdx.x * BINS + j];
        px[threadIdx.x] = r;
    } else if (threadIdx.x < 64) {
        int col = threadIdx.x - 32;
        unsigned r = 0;
        for (int j = 0; j < 32; ++j) r += c[j * BINS + col];
        py[col] = r;
    }
    __syncthreads();

    unsigned total = 0;
    for (int j = 0; j < 32; ++j) total += px[j];
    const double T = (double)total;

    double acc = 0.0;
    {
        unsigned cc = c[threadIdx.x];
        if (cc) {
            int r = threadIdx.x >> 5, col = threadIdx.x & 31;
            acc = (double)cc * log((double)cc * T / ((double)px[r] * (double)py[col]));
        }
    }
    // wave (64-lane) shuffle reduction, fixed order -> deterministic
    for (int off = 32; off > 0; off >>= 1)
        acc += __shfl_down(acc, off, 64);
    int wave = threadIdx.x >> 6;
    if ((threadIdx.x & 63) == 0) red[wave] = acc;
    __syncthreads();
    if (threadIdx.x == 0) {
        double t = 0.0;
        for (int i = 0; i < 16; ++i) t += red[i];
        mi_out[b] = t / T;
    }
}

__global__ void finalize_kernel(const double* __restrict__ mi, float* __restrict__ out) {
    if (threadIdx.x == 0) {
        double s = 0.0;
        for (int i = 0; i < NBATCH; ++i) s += mi[i];
        out[0] = (float)(-s / (double)NBATCH);
    }
}

extern "C" void kernel_launch(void* const* d_in, const int* in_sizes, int n_in,
                              void* d_out, int out_size, void* d_ws, size_t ws_size,
                              hipStream_t stream) {
    const float* x = (const float*)d_in[0];
    const float* y = (const float*)d_in[1];
    float* out = (float*)d_out;

    unsigned* parts = (unsigned*)d_ws;

    // Pick blocks-per-batch by available workspace (deterministic: ws_size fixed).
    int bpb;
    if (ws_size >= (size_t)NBATCH * 64 * NBINS2 * sizeof(unsigned) + 256) bpb = 64;
    else if (ws_size >= (size_t)NBATCH * 16 * NBINS2 * sizeof(unsigned) + 256) bpb = 16;
    else bpb = 4;

    double* mi = (double*)((char*)d_ws + (size_t)NBATCH * bpb * NBINS2 * sizeof(unsigned));

    switch (bpb) {
        case 64: hist_kernel<64><<<NBATCH * 64, THREADS, 0, stream>>>(x, y, parts); break;
        case 16: hist_kernel<16><<<NBATCH * 16, THREADS, 0, stream>>>(x, y, parts); break;
        default: hist_kernel<4><<<NBATCH * 4, THREADS, 0, stream>>>(x, y, parts); break;
    }
    mi_kernel<<<NBATCH, 1024, 0, stream>>>(parts, bpb, mi);
    finalize_kernel<<<1, 64, 0, stream>>>(mi, out);
}

// Round 4
// 35.650 us; speedup vs baseline: 1.0806x; 1.0001x over previous
//
#include <hip/hip_runtime.h>

// MutualInformation2D: B=32 batches, N=2*512*512=524288 points/batch.
// Per-block private histograms (plain stores, NO global atomics) -> per-batch
// integer reduction + MI in double -> scalar out = -mean(mi).
// R4: block-cyclic interleaved reads within each batch (channel balance).

#define BINS 32
#define NBINS2 1024
#define LDS_ROW 33                       // padded row stride: bank = (iu+iv)%32
#define LDS_HIST (BINS * LDS_ROW)        // 1056
#define NBATCH 32
#define N_PER_BATCH (2 * 512 * 512)      // 524288 floats per batch
#define NVEC_BATCH (N_PER_BATCH / 4)     // 131072 float4 per batch
#define BPB 64                           // blocks per batch
#define THREADS 256
#define VPT 8                            // float4 per thread per array (131072/(64*256))

__global__ __launch_bounds__(THREADS) void hist_kernel(const float* __restrict__ x,
                                                       const float* __restrict__ y,
                                                       unsigned* __restrict__ parts) {
    __shared__ unsigned h[LDS_HIST];
    for (int i = threadIdx.x; i < LDS_HIST; i += THREADS) h[i] = 0u;
    __syncthreads();

    const int b   = blockIdx.x >> 6;     // / BPB
    const int blk = blockIdx.x & 63;     // % BPB
    const float4* xb = (const float4*)x + (size_t)b * NVEC_BATCH;
    const float4* yb = (const float4*)y + (size_t)b * NVEC_BATCH;

    // Block-cyclic interleave: iteration j's window (64 blocks x 256 threads)
    // is a CONTIGUOUS 1 MiB span of the batch; the in-flight address set is
    // uniform over the whole input -> balanced HBM/L3 channels.
    const int off = blk * THREADS + threadIdx.x;
    float4 xa[VPT], ya[VPT];
#pragma unroll
    for (int j = 0; j < VPT; ++j) xa[j] = xb[(size_t)j * (BPB * THREADS) + off];
#pragma unroll
    for (int j = 0; j < VPT; ++j) ya[j] = yb[(size_t)j * (BPB * THREADS) + off];

#pragma unroll
    for (int j = 0; j < VPT; ++j) {
        float ax[4] = {xa[j].x, xa[j].y, xa[j].z, xa[j].w};
        float ty[4] = {ya[j].x, ya[j].y, ya[j].z, ya[j].w};
#pragma unroll
        for (int k = 0; k < 4; ++k) {
            // Exact float32 replication of the reference binning.
            float u = (ax[k] + 1.0f) * 0.5f;
            float v = (ty[k] + 1.0f) * 0.5f;
            bool ok = (u >= 0.0f) & (u <= 1.0f) & (v >= 0.0f) & (v <= 1.0f);
            if (ok) {
                int iu = (int)(u * 32.0f); if (iu > 31) iu = 31;
                int iv = (int)(v * 32.0f); if (iv > 31) iv = 31;
                atomicAdd(&h[iu * LDS_ROW + iv], 1u);
            }
        }
    }
    __syncthreads();

    // Plain coalesced stores of the private histogram — no global atomics.
    unsigned* g = parts + (size_t)blockIdx.x * NBINS2;
    for (int i = threadIdx.x; i < NBINS2; i += THREADS)
        g[i] = h[(i >> 5) * LDS_ROW + (i & 31)];
}

__global__ __launch_bounds__(1024) void mi_kernel(const unsigned* __restrict__ parts,
                                                  int nparts,
                                                  double* __restrict__ mi_out) {
    __shared__ unsigned c[NBINS2];
    __shared__ unsigned px[BINS];
    __shared__ unsigned py[BINS];
    __shared__ double red[16];

    const int b = blockIdx.x;
    // Reduce partials: thread i owns bin i. Integer adds -> order-independent.
    const unsigned* base = parts + (size_t)b * nparts * NBINS2 + threadIdx.x;
    unsigned s = 0;
#pragma unroll 8
    for (int p = 0; p < nparts; ++p) s += base[(size_t)p * NBINS2];
    c[threadIdx.x] = s;
    __syncthreads();

    if (threadIdx.x < 32) {
        unsigned r = 0;
        for (int j = 0; j < 32; ++j) r += c[threadIdx.x * BINS + j];
        px[threadIdx.x] = r;
    } else if (threadIdx.x < 64) {
        int col = threadIdx.x - 32;
        unsigned r = 0;
        for (int j = 0; j < 32; ++j) r += c[j * BINS + col];
        py[col] = r;
    }
    __syncthreads();

    unsigned total = 0;
    for (int j = 0; j < 32; ++j) total += px[j];
    const double T = (double)total;

    double acc = 0.0;
    {
        unsigned cc = c[threadIdx.x];
        if (cc) {
            int r = threadIdx.x >> 5, col = threadIdx.x & 31;
            acc = (double)cc * log((double)cc * T / ((double)px[r] * (double)py[col]));
        }
    }
    // wave (64-lane) shuffle reduction, fixed order -> deterministic
    for (int off = 32; off > 0; off >>= 1)
        acc += __shfl_down(acc, off, 64);
    int wave = threadIdx.x >> 6;
    if ((threadIdx.x & 63) == 0) red[wave] = acc;
    __syncthreads();
    if (threadIdx.x == 0) {
        double t = 0.0;
        for (int i = 0; i < 16; ++i) t += red[i];
        mi_out[b] = t / T;
    }
}

__global__ void finalize_kernel(const double* __restrict__ mi, float* __restrict__ out) {
    if (threadIdx.x == 0) {
        double s = 0.0;
        for (int i = 0; i < NBATCH; ++i) s += mi[i];
        out[0] = (float)(-s / (double)NBATCH);
    }
}

extern "C" void kernel_launch(void* const* d_in, const int* in_sizes, int n_in,
                              void* d_out, int out_size, void* d_ws, size_t ws_size,
                              hipStream_t stream) {
    const float* x = (const float*)d_in[0];
    const float* y = (const float*)d_in[1];
    float* out = (float*)d_out;

    unsigned* parts = (unsigned*)d_ws;   // 32*64*1024*4 = 8 MiB
    double* mi = (double*)((char*)d_ws + (size_t)NBATCH * BPB * NBINS2 * sizeof(unsigned));

    hist_kernel<<<NBATCH * BPB, THREADS, 0, stream>>>(x, y, parts);
    mi_kernel<<<NBATCH, 1024, 0, stream>>>(parts, BPB, mi);
    finalize_kernel<<<1, 64, 0, stream>>>(mi, out);
}